// Round 10
// baseline (521.922 us; speedup 1.0000x reference)
//
#include <hip/hip_runtime.h>
#include <hip/hip_bf16.h>
#include <math.h>

typedef unsigned short ushort_t;
typedef __attribute__((ext_vector_type(8))) short bf16x8;
typedef __attribute__((ext_vector_type(4))) float f32x4;

#define LOG2E 1.4426950408889634f

// ---------------- helpers ----------------
__device__ __forceinline__ float sigf(float x) {
  x = fminf(fmaxf(x, -30.f), 30.f);
  return 1.f / (1.f + __expf(-x));
}
__device__ __forceinline__ ushort_t f2bf(float x) {
  unsigned int b = __float_as_uint(x);
  unsigned int lsb = (b >> 16) & 1u;
  b += 0x7fffu + lsb;
  return (ushort_t)(b >> 16);
}
__device__ __forceinline__ float bf2f(ushort_t u) {
  return __uint_as_float(((unsigned int)u) << 16);
}
// gate scale for exp2-form activations: rows of gate g (pos&3==2) carry
// 2*log2e, others log2e. Applied at every pre-activation producer.
__device__ __forceinline__ float gsc(int g3) {
  return (g3 == 2) ? (2.f * LOG2E) : LOG2E;
}

#define NPIX 3600
// gate-row permutation: LSTM row-space position rho holds real gate row
// G(rho) = (rho&3)*128 + (rho>>2)  => per cell c, gates i,f,g,o sit at
// positions 4c..4c+3.
__device__ __forceinline__ int gperm(int rho) {
  return ((rho & 3) << 7) + (rho >> 2);
}

// ---- front: wprep (blocks 0-1988) + box stats (1989-6788) ------------------
__global__ __launch_bounds__(256) void front_kernel(
    const float* __restrict__ mv, const float* __restrict__ boxes,
    const int* __restrict__ ids, const float* __restrict__ agg_w1,
    const float* __restrict__ agg_b1, const float* __restrict__ agg_w2,
    const float* __restrict__ agg_b2, const float* __restrict__ bx_w1,
    const float* __restrict__ bx_b1, const float* __restrict__ bx_w2,
    const float* __restrict__ bx_b2, const float* __restrict__ id_table,
    ushort_t* __restrict__ obj_out, const float* __restrict__ conv2_w,
    const float* __restrict__ conv3_w, const float* __restrict__ wih0,
    const float* __restrict__ projW, const float* __restrict__ projb,
    const float* __restrict__ l0_b, const float* __restrict__ hbw1,
    const float* __restrict__ hcw1, const float* __restrict__ htw1,
    const float* __restrict__ htw2, const float* __restrict__ hbb1,
    const float* __restrict__ hcb1, const float* __restrict__ htb1,
    ushort_t* __restrict__ wc2, ushort_t* __restrict__ wc3,
    ushort_t* __restrict__ wAp, float* __restrict__ l0bp,
    ushort_t* __restrict__ whid, ushort_t* __restrict__ wt2,
    float* __restrict__ bhid) {
  if (blockIdx.x < 1989) {
    // ---- weight prep ----
    int i = blockIdx.x * 256 + threadIdx.x;
    if (i < 18432) {  // conv2 w -> [oc][kt][ic] bf16
      int oc = i / 288, r = i % 288, kt = r / 32, ic = r % 32;
      wc2[i] = f2bf(conv2_w[((oc * 32 + ic) * 3 + kt / 3) * 3 + kt % 3]);
      return;
    }
    i -= 18432;
    if (i < 36864) {  // conv3 w -> [oc][c][kt][ic] bf16
      int oc = i / 576, r = i % 576, c = r / 288, r2 = r % 288;
      int kt = r2 / 32, icl = r2 % 32, ic = c * 32 + icl;
      wc3[i] = f2bf(conv3_w[((oc * 64 + ic) * 3 + kt / 3) * 3 + kt % 3]);
      return;
    }
    i -= 36864;
    if (i < 98304) {  // W' = wih0[:, :128] @ projW, permuted + gate-scaled
      int n = i / 192, k = i % 192;
      int src = gperm(n);
      float a = 0.f;
      if (k < 160) {
        const float* wr = wih0 + src * 192;
        for (int j = 0; j < 128; ++j) a = fmaf(wr[j], projW[j * 160 + k], a);
      }
      wAp[i] = f2bf(a * gsc(n & 3));
      return;
    }
    i -= 98304;
    if (i < 512) {  // l0b' = l0_b + wih0[:, :128] @ proj_b, permuted + scaled
      int src = gperm(i);
      float a = l0_b[src];
      const float* wr = wih0 + src * 192;
      for (int j = 0; j < 128; ++j) a = fmaf(wr[j], projb[j], a);
      l0bp[i] = a * gsc(i & 3);
      return;
    }
    i -= 512;
    if (i < 98304) {  // concat head hidden weights
      int row = i >> 7, c = i & 127;
      float v = (row < 256)   ? hbw1[row * 128 + c]
                : (row < 512) ? hcw1[(row - 256) * 128 + c]
                              : htw1[(row - 512) * 128 + c];
      whid[i] = f2bf(v);
      return;
    }
    i -= 98304;
    if (i < 256000) {
      wt2[i] = f2bf(htw2[i]);
      return;
    }
    i -= 256000;
    if (i < 768)
      bhid[i] = (i < 256) ? hbb1[i] : (i < 512) ? hcb1[i - 256] : htb1[i - 512];
    return;
  }
  // ---- box stats + small MLPs: 2 boxes per block ----
  int bx = blockIdx.x - 1989;
  __shared__ float obj[2][160];
  __shared__ float hm[2][32];
  __shared__ float hbx[2][32];
  __shared__ float stats[2][8];
  __shared__ float boxf[2][4];
  __shared__ float red[2][2][8];
  int h = threadIdx.x >> 7;
  int t = threadIdx.x & 127;
  int blk = bx * 2 + h;  // box index 0..9599
  int b = blk / 300;
  float bx0 = boxes[blk * 4 + 0], by0 = boxes[blk * 4 + 1];
  float bx1 = boxes[blk * 4 + 2], by1 = boxes[blk * 4 + 3];
  const float HI = (float)(60.0 - 1e-6);
  float gx1 = fminf(fmaxf(bx0 * 60.f, 0.f), HI);
  float gy1 = fminf(fmaxf(by0 * 60.f, 0.f), HI);
  float gx2 = fminf(fmaxf(bx1 * 60.f, 0.f), HI);
  float gy2 = fminf(fmaxf(by1 * 60.f, 0.f), HI);
  float fx1 = floorf(gx1), fy1 = floorf(gy1);
  float fx2 = fmaxf(fx1 + 1.f, ceilf(gx2));
  float fy2 = fmaxf(fy1 + 1.f, ceilf(gy2));
  int ix1 = (int)fx1, iy1 = (int)fy1, ix2 = (int)fx2, iy2 = (int)fy2;
  int w = ix2 - ix1, hgt = iy2 - iy1;
  int area = w * hgt;
  float s0 = 0.f, s1 = 0.f, q0 = 0.f, q1 = 0.f;
  float mn0 = 1e9f, mn1 = 1e9f, mx0 = -1e9f, mx1 = -1e9f;
  const float* mv0 = mv + b * 2 * NPIX;
  const float* mv1 = mv0 + NPIX;
  for (int i = t; i < area; i += 128) {
    int r = i / w, cc = i - r * w;
    int yy = iy1 + r, xx = ix1 + cc;
    float v0 = mv0[yy * 60 + xx];
    float v1 = mv1[yy * 60 + xx];
    s0 += v0; q0 += v0 * v0; mn0 = fminf(mn0, v0); mx0 = fmaxf(mx0, v0);
    s1 += v1; q1 += v1 * v1; mn1 = fminf(mn1, v1); mx1 = fmaxf(mx1, v1);
  }
#pragma unroll
  for (int off = 32; off; off >>= 1) {
    s0 += __shfl_down(s0, off); s1 += __shfl_down(s1, off);
    q0 += __shfl_down(q0, off); q1 += __shfl_down(q1, off);
    mn0 = fminf(mn0, __shfl_down(mn0, off));
    mn1 = fminf(mn1, __shfl_down(mn1, off));
    mx0 = fmaxf(mx0, __shfl_down(mx0, off));
    mx1 = fmaxf(mx1, __shfl_down(mx1, off));
  }
  if ((t & 63) == 0) {
    int wv = t >> 6;
    red[h][wv][0] = s0; red[h][wv][1] = s1;
    red[h][wv][2] = q0; red[h][wv][3] = q1;
    red[h][wv][4] = mn0; red[h][wv][5] = mn1;
    red[h][wv][6] = mx0; red[h][wv][7] = mx1;
  }
  __syncthreads();
  if (t == 0) {
    float S0 = red[h][0][0] + red[h][1][0], S1 = red[h][0][1] + red[h][1][1];
    float Q0 = red[h][0][2] + red[h][1][2], Q1 = red[h][0][3] + red[h][1][3];
    float MN0 = fminf(red[h][0][4], red[h][1][4]);
    float MN1 = fminf(red[h][0][5], red[h][1][5]);
    float MX0 = fmaxf(red[h][0][6], red[h][1][6]);
    float MX1 = fmaxf(red[h][0][7], red[h][1][7]);
    float cnt = (float)area;
    float mean0 = S0 / cnt, mean1 = S1 / cnt;
    float var0 = (Q0 - cnt * mean0 * mean0) / fmaxf(cnt - 1.f, 1.f);
    float var1 = (Q1 - cnt * mean1 * mean1) / fmaxf(cnt - 1.f, 1.f);
    float sd0 = (cnt > 1.f) ? sqrtf(fmaxf(var0, 1e-12f)) : 0.f;
    float sd1 = (cnt > 1.f) ? sqrtf(fmaxf(var1, 1e-12f)) : 0.f;
    stats[h][0] = mean0; stats[h][1] = mean1; stats[h][2] = sd0;
    stats[h][3] = sd1; stats[h][4] = MN0; stats[h][5] = MX0;
    stats[h][6] = MN1; stats[h][7] = MX1;
    boxf[h][0] = bx0; boxf[h][1] = by0; boxf[h][2] = bx1; boxf[h][3] = by1;
  }
  __syncthreads();
  if (t < 32) {
    float a = agg_b1[t];
#pragma unroll
    for (int k = 0; k < 8; ++k) a = fmaf(stats[h][k], agg_w1[t * 8 + k], a);
    hm[h][t] = fmaxf(a, 0.f);
  } else if (t < 64) {
    int j = t - 32;
    float a = bx_b1[j];
#pragma unroll
    for (int k = 0; k < 4; ++k) a = fmaf(boxf[h][k], bx_w1[j * 4 + k], a);
    hbx[h][j] = fmaxf(a, 0.f);
  }
  __syncthreads();
  if (t < 64) {
    float a = bx_b2[t];
#pragma unroll
    for (int k = 0; k < 32; ++k) a = fmaf(hbx[h][k], bx_w2[t * 32 + k], a);
    obj[h][t] = a;
  } else {
    int j = t - 64;
    float a = agg_b2[j];
#pragma unroll
    for (int k = 0; k < 32; ++k) a = fmaf(hm[h][k], agg_w2[j * 32 + k], a);
    obj[h][96 + j] = a;
  }
  if (t < 32) {
    int id = ids[blk];
    id = min(max(id, 0), 999);
    obj[h][64 + t] = id_table[id * 32 + t];
  }
  __syncthreads();
  obj_out[(size_t)blk * 192 + t] = f2bf(obj[h][t]);
  if (t < 32) {
    obj_out[(size_t)blk * 192 + 128 + t] = f2bf(obj[h][128 + t]);
    obj_out[(size_t)blk * 192 + 160 + t] = 0;
  }
}

// ---------- fused conv1+conv2+conv3+avgpool: one block = 14x14 out tile -----
__global__ __launch_bounds__(256) void convstack_kernel(
    const float* __restrict__ mv, const float* __restrict__ c1w,
    const float* __restrict__ c1b, const float* __restrict__ bg1,
    const float* __restrict__ bb1, const ushort_t* __restrict__ wc2,
    const float* __restrict__ c2b, const float* __restrict__ bg2,
    const float* __restrict__ bb2, const ushort_t* __restrict__ wc3,
    const float* __restrict__ c3b, const float* __restrict__ bg3,
    const float* __restrict__ bb3, float* __restrict__ gf) {
  __shared__ char smem[25920 + 37152];           // 63,072 B
  ushort_t* c1_lds = (ushort_t*)smem;            // [324][40] bf16
  ushort_t* c2_lds = (ushort_t*)(smem + 25920);  // [258][72] bf16 (+2 pad pos)
  float* mv_lds = (float*)(smem + 25920);        // [2][20][20] (aliases c2)
  int tid = threadIdx.x;
  int wv = tid >> 6, lane = tid & 63;
  int col = lane & 15, kg = lane >> 4;
  int b = blockIdx.y, tile = blockIdx.x;
  int tq = tile / 5, tr = tile % 5;
  int ty0 = (tq == 4) ? 46 : tq * 14;
  int tx0 = (tr == 4) ? 46 : tr * 14;
  // stage mv rows [ty0-3, ty0+16] x cols [tx0-3, tx0+16], zero-padded
  for (int i = tid; i < 800; i += 256) {
    int r = i % 400;
    int ch = i / 400, yy = r / 20, xx = r % 20;
    int gy = ty0 - 3 + yy, gx = tx0 - 3 + xx;
    float v = 0.f;
    if (gy >= 0 && gy < 60 && gx >= 0 && gx < 60)
      v = mv[((size_t)(b * 2 + ch) * 60 + gy) * 60 + gx];
    mv_lds[i] = v;
  }
  __syncthreads();
  // conv1 (2->32, BN+ReLU): 18x18 out, rows [ty0-2, ty0+15]
  {
    int oc = tid & 31;
    float s = bg1[oc] * rsqrtf(1.f + 1e-5f);
    float bias = fmaf(c1b[oc], s, bb1[oc]);
    float w1r[18];
#pragma unroll
    for (int k = 0; k < 18; ++k) w1r[k] = c1w[oc * 18 + k];
    for (int pos = tid >> 5; pos < 324; pos += 8) {
      int yy = pos / 18, xx = pos % 18;
      int gy = ty0 - 2 + yy, gx = tx0 - 2 + xx;
      ushort_t out = 0;
      if (gy >= 0 && gy < 60 && gx >= 0 && gx < 60) {
        float acc = 0.f;
#pragma unroll
        for (int ic = 0; ic < 2; ++ic)
#pragma unroll
          for (int ky = 0; ky < 3; ++ky)
#pragma unroll
            for (int kx = 0; kx < 3; ++kx)
              acc = fmaf(mv_lds[ic * 400 + (yy + ky) * 20 + xx + kx],
                         w1r[ic * 9 + ky * 3 + kx], acc);
        out = f2bf(fmaxf(fmaf(acc, s, bias), 0.f));
      }
      c1_lds[pos * 40 + oc] = out;
    }
  }
  __syncthreads();  // conv1 done; mv reads done (c2_lds aliasing now safe)
  int oc2 = wv * 16 + col;
  // conv2 (32->64, MFMA, BN+ReLU): 16x16 out, rows [ty0-1, ty0+14]
  {
    bf16x8 bw2[9];
#pragma unroll
    for (int kt = 0; kt < 9; ++kt)
      bw2[kt] = *(const bf16x8*)(wc2 + oc2 * 288 + kt * 32 + kg * 8);
    f32x4 a2[16];
#pragma unroll
    for (int m = 0; m < 16; ++m) a2[m] = (f32x4){0.f, 0.f, 0.f, 0.f};
#pragma unroll
    for (int kt = 0; kt < 9; ++kt) {
      int ky = kt / 3, kx = kt % 3;
#pragma unroll
      for (int m = 0; m < 16; ++m) {
        bf16x8 af = *(const bf16x8*)(
            &c1_lds[((m + ky) * 18 + col + kx) * 40 + kg * 8]);
        a2[m] =
            __builtin_amdgcn_mfma_f32_16x16x32_bf16(af, bw2[kt], a2[m], 0, 0, 0);
      }
    }
    float s = bg2[oc2] * rsqrtf(1.f + 1e-5f);
    float bias = fmaf(c2b[oc2], s, bb2[oc2]);
#pragma unroll
    for (int m = 0; m < 16; ++m) {
      int gy = ty0 - 1 + m;
#pragma unroll
      for (int r = 0; r < 4; ++r) {
        int gx = tx0 - 1 + kg * 4 + r;
        ushort_t o = 0;
        if (gy >= 0 && gy < 60 && gx >= 0 && gx < 60)
          o = f2bf(fmaxf(fmaf(a2[m][r], s, bias), 0.f));
        c2_lds[(m * 16 + kg * 4 + r) * 72 + oc2] = o;
      }
    }
  }
  __syncthreads();
  // conv3 (64->64, MFMA, BN+ReLU) + masked avgpool accumulate
  {
    bf16x8 bw3[2][9];
#pragma unroll
    for (int c = 0; c < 2; ++c)
#pragma unroll
      for (int kt = 0; kt < 9; ++kt)
        bw3[c][kt] =
            *(const bf16x8*)(wc3 + oc2 * 576 + c * 288 + kt * 32 + kg * 8);
    f32x4 a3[14];
#pragma unroll
    for (int m = 0; m < 14; ++m) a3[m] = (f32x4){0.f, 0.f, 0.f, 0.f};
#pragma unroll
    for (int c = 0; c < 2; ++c)
#pragma unroll
      for (int kt = 0; kt < 9; ++kt) {
        int ky = kt / 3, kx = kt % 3;
#pragma unroll
        for (int m = 0; m < 14; ++m) {
          bf16x8 af = *(const bf16x8*)(
              &c2_lds[((m + ky) * 16 + col + kx) * 72 + c * 32 + kg * 8]);
          a3[m] = __builtin_amdgcn_mfma_f32_16x16x32_bf16(af, bw3[c][kt],
                                                          a3[m], 0, 0, 0);
        }
      }
    float s = bg3[oc2] * rsqrtf(1.f + 1e-5f);
    float bias = fmaf(c3b[oc2], s, bb3[oc2]);
    float pool = 0.f;
#pragma unroll
    for (int m = 0; m < 14; ++m) {
      bool ym = (tq != 4) || (m >= 10);
#pragma unroll
      for (int r = 0; r < 4; ++r) {
        int px = kg * 4 + r;
        bool xm = (px < 14) && ((tr != 4) || (px >= 10));
        if (ym && xm) pool += fmaxf(fmaf(a3[m][r], s, bias), 0.f);
      }
    }
    pool += __shfl_xor(pool, 16);
    pool += __shfl_xor(pool, 32);
    if (lane < 16) atomicAdd(&gf[b * 64 + oc2], pool);
  }
}

// ---------------- bf16-W MFMA GEMM: C = act(A@W^T + b [+ gvec]) -------------
template <int ACT, bool OBF16, bool GVEC>
__global__ __launch_bounds__(256) void gemm_bf16w_kernel(
    const ushort_t* __restrict__ A, int lda, const ushort_t* __restrict__ W,
    const float* __restrict__ bias, void* __restrict__ C, int ldc, int M,
    int N, int K, const float* __restrict__ wih0,
    const float* __restrict__ gf) {
  __shared__ ushort_t As[128 * 64];
  __shared__ ushort_t Ws[64 * 64];
  __shared__ float gvl[2][64];
  int tid = threadIdx.x;
  int wv = tid >> 6, lane = tid & 63;
  int col = lane & 15, kg = lane >> 4;
  int wm = wv >> 1, wn = wv & 1;
  int m0 = blockIdx.x * 128, n0 = blockIdx.y * 64;
  int bA = m0 / 300;
  if (GVEC && tid < 128) {
    int sel = tid >> 6;  // 0/1: batch bA / bA+1
    int nn = tid & 63;
    int n = n0 + nn;
    int bb = min(bA + sel, 31);
    const float* wr = wih0 + gperm(n) * 192 + 128;
    const float* gg = gf + bb * 64;
    float a = 0.f;
#pragma unroll
    for (int k = 0; k < 64; ++k) a = fmaf(wr[k], gg[k], a);
    gvl[sel][nn] = a * (1.f / 3600.f) * gsc(n & 3);
  }
  f32x4 acc[4][2];
#pragma unroll
  for (int i = 0; i < 4; ++i)
#pragma unroll
    for (int j = 0; j < 2; ++j) acc[i][j] = (f32x4){0.f, 0.f, 0.f, 0.f};

  int nk = K >> 6;
  for (int kc = 0; kc < nk; ++kc) {
    if (kc) __syncthreads();
#pragma unroll
    for (int q = 0; q < 4; ++q) {
      int idx = q * 256 + tid;
      int row = idx >> 3, ch = idx & 7;
      uint4 v =
          *(const uint4*)(A + (size_t)(m0 + row) * lda + kc * 64 + ch * 8);
      *(uint4*)(&As[row * 64 + ((ch * 8) ^ ((row & 7) << 3))]) = v;
    }
#pragma unroll
    for (int q = 0; q < 2; ++q) {
      int idx = q * 256 + tid;
      int row = idx >> 3, ch = idx & 7;
      int n = n0 + row;
      uint4 v = make_uint4(0, 0, 0, 0);
      if (n < N) v = *(const uint4*)(W + (size_t)n * K + kc * 64 + ch * 8);
      *(uint4*)(&Ws[row * 64 + ((ch * 8) ^ ((row & 7) << 3))]) = v;
    }
    __syncthreads();
#pragma unroll
    for (int ks = 0; ks < 2; ++ks) {
      bf16x8 bfr[2], afr[4];
#pragma unroll
      for (int ni = 0; ni < 2; ++ni) {
        int row = wn * 32 + ni * 16 + col;
        bfr[ni] = *(const bf16x8*)(
            &Ws[row * 64 + ((ks * 32 + kg * 8) ^ ((row & 7) << 3))]);
      }
#pragma unroll
      for (int mi = 0; mi < 4; ++mi) {
        int row = wm * 64 + mi * 16 + col;
        afr[mi] = *(const bf16x8*)(
            &As[row * 64 + ((ks * 32 + kg * 8) ^ ((row & 7) << 3))]);
      }
#pragma unroll
      for (int mi = 0; mi < 4; ++mi)
#pragma unroll
        for (int ni = 0; ni < 2; ++ni)
          acc[mi][ni] = __builtin_amdgcn_mfma_f32_16x16x32_bf16(
              afr[mi], bfr[ni], acc[mi][ni], 0, 0, 0);
    }
  }
#pragma unroll
  for (int ni = 0; ni < 2; ++ni) {
    int n = n0 + wn * 32 + ni * 16 + col;
    float bn = (n < N) ? bias[n] : 0.f;
#pragma unroll
    for (int mi = 0; mi < 4; ++mi) {
      int mbase = m0 + wm * 64 + mi * 16 + kg * 4;
#pragma unroll
      for (int r = 0; r < 4; ++r) {
        float v = acc[mi][ni][r] + bn;
        if (GVEC) v += gvl[(mbase + r) / 300 - bA][wn * 32 + ni * 16 + col];
        if (ACT == 1) v = fmaxf(v, 0.f);
        if (n < N) {
          if (OBF16)
            ((ushort_t*)C)[(size_t)(mbase + r) * ldc + n] = f2bf(v);
          else
            ((float*)C)[(size_t)(mbase + r) * ldc + n] = v;
        }
      }
    }
  }
}

// ---------------- small heads: hb2 (sigmoid, N=4) + hc2 (N=2) ---------------
__global__ __launch_bounds__(256) void head_small_kernel(
    const ushort_t* __restrict__ hid, const float* __restrict__ wb2,
    const float* __restrict__ bb2, const float* __restrict__ wc2,
    const float* __restrict__ bc2, float* __restrict__ outB,
    float* __restrict__ outC) {
  int idx = blockIdx.x * 256 + threadIdx.x;  // 9600*6
  int row = idx / 6, j = idx % 6;
  const ushort_t* h = hid + (size_t)row * 768 + (j < 4 ? 0 : 256);
  const float* wrow = (j < 4) ? wb2 + j * 256 : wc2 + (j - 4) * 256;
  float acc = (j < 4) ? bb2[j] : bc2[j - 4];
  for (int k = 0; k < 256; k += 8) {
    uint4 hv = *(const uint4*)(h + k);
    unsigned int ww[4] = {hv.x, hv.y, hv.z, hv.w};
#pragma unroll
    for (int q = 0; q < 4; ++q) {
      acc = fmaf(bf2f((ushort_t)(ww[q] & 0xffff)), wrow[k + 2 * q], acc);
      acc = fmaf(bf2f((ushort_t)(ww[q] >> 16)), wrow[k + 2 * q + 1], acc);
    }
  }
  float v = (j < 4) ? sigf(acc) : acc;
  if (j < 4) outB[row * 4 + j] = v;
  else outC[row * 2 + (j - 4)] = v;
}

// -------- fused 2-layer LSTM scan v14: L0+L1 MERGED per block ---------------
// Waves 0-7 = L0 (step p), waves 8-15 = L1 (step t = p-LAG), sharing ONE
// barrier per period -> 4 waves/SIMD on each scan CU (vs 2 before), so one
// layer's MFMA/LDS/VALU fills the other's latency bubbles (v8 showed fewer
// waves/SIMD hurt; this doubles them at unchanged per-wave work).
// LAG=24: chunk t0's flag1=t0+12 publishes by ~period t0+17; L1 needs
// flag1>=t+3 at period t+24 -> >=7 periods slack, so the shared barrier
// (which couples L0 to L1's flag polls) never stalls in steady state.
// Periods = 300+LAG = 324. L0 publishes flag0=p-3 after vmcnt(6) (y0
// visibility proof unchanged); at p==300 a vmcnt(0) lets it publish 300.
// u-blocks (blockIdx 8-15): unchanged logic on tid<512; upper waves only
// rendezvous at the per-chunk __syncthreads (25 chunks).
#define LSTM_BAR() asm volatile("s_waitcnt lgkmcnt(0)\n\ts_barrier" ::: "memory")
#define LSTM_LAG 24

__global__ __launch_bounds__(1024, 1) void lstm_fused_kernel(
    const float* __restrict__ pre0,  // [32][300][512] f32, permuted+scaled
    const float* __restrict__ whh0,  // [512,128]
    const float* __restrict__ wih1,  // [512,128]
    const float* __restrict__ whh1,  // [512,128]
    const float* __restrict__ b1,    // [512]
    float* __restrict__ pre1,        // [32][300][512] f32, permuted+scaled
    ushort_t* __restrict__ y0,       // [32][300][128] bf16 (L0 -> u)
    ushort_t* __restrict__ y1,       // [32][300][128] bf16
    float* __restrict__ outH, float* __restrict__ outC,
    unsigned int* __restrict__ flags)  // [8*32] padded
{
  __shared__ ushort_t h0_lds[2][4][160];
  __shared__ ushort_t h1_lds[2][4][160];
  int tid = threadIdx.x;
  int ltid = tid & 511;
  int w = ltid >> 6, lane = ltid & 63;
  int col = lane & 15, kg = lane >> 4;
  int bat = col & 3, q = col >> 2;
  int cell = (4 * w + q) * 4 + kg;
  float wsc = gsc(col & 3);  // A-row = col -> gate = col&3

  if (blockIdx.x < 8) {
    int g = blockIdx.x;
    int b0 = g * 4;
    unsigned int* flag0 = &flags[g * 32];
    unsigned int* flag1 = &flags[g * 32 + 16];
    for (int i = tid; i < 2 * 4 * 160; i += 1024) {
      ((ushort_t*)h0_lds)[i] = 0;
      ((ushort_t*)h1_lds)[i] = 0;
    }
    if (tid < 512) {
      // ---------------- layer 0 waves ----------------
      bf16x8 aW0[4][4];
#pragma unroll
      for (int j = 0; j < 4; ++j) {
        int rho = (4 * w + j) * 16 + col;
        int src = gperm(rho);
#pragma unroll
        for (int kt = 0; kt < 4; ++kt) {
          const float* s1 = whh0 + src * 128 + kt * 32 + kg * 8;
          bf16x8 f1;
#pragma unroll
          for (int qq = 0; qq < 8; ++qq) f1[qq] = (short)f2bf(s1[qq] * wsc);
          aW0[j][kt] = f1;
        }
      }
      const float* pg = pre0 + (size_t)(b0 + bat) * 300 * 512 + 4 * cell;
      ushort_t* yg0 = y0 + ((size_t)(b0 + bat) * 300) * 128 + cell;
      float c = 0.f, hout = 0.f;
      f32x4 p0v = *(const f32x4*)(pg);
      f32x4 p1v = *(const f32x4*)(pg + 512);
      __syncthreads();

      for (int p = 0; p < 300 + LSTM_LAG; ++p) {
        if (p < 300) {
          const ushort_t* hb = h0_lds[p & 1][bat];
          bf16x8 bfr[4];
#pragma unroll
          for (int kt = 0; kt < 4; ++kt)
            bfr[kt] = *(const bf16x8*)(hb + kt * 32 + kg * 8);
          f32x4 a0 = {0.f, 0.f, 0.f, 0.f}, a1 = a0, a2 = a0, a3 = a0;
#pragma unroll
          for (int kt = 0; kt < 4; ++kt) {
            a0 = __builtin_amdgcn_mfma_f32_16x16x32_bf16(aW0[0][kt], bfr[kt], a0, 0, 0, 0);
            a1 = __builtin_amdgcn_mfma_f32_16x16x32_bf16(aW0[1][kt], bfr[kt], a1, 0, 0, 0);
            a2 = __builtin_amdgcn_mfma_f32_16x16x32_bf16(aW0[2][kt], bfr[kt], a2, 0, 0, 0);
            a3 = __builtin_amdgcn_mfma_f32_16x16x32_bf16(aW0[3][kt], bfr[kt], a3, 0, 0, 0);
          }
          f32x4 z = a0;
          if (q == 1) z = a1;
          if (q == 2) z = a2;
          if (q == 3) z = a3;
          float zi = z[0] + p0v[0];
          float zf = z[1] + p0v[1];
          float zg = z[2] + p0v[2];
          float zo = z[3] + p0v[3];
          float vi = __builtin_amdgcn_rcpf(1.f + __builtin_amdgcn_exp2f(-zi));
          float vf = __builtin_amdgcn_rcpf(1.f + __builtin_amdgcn_exp2f(-zf));
          float vg = 1.f - 2.f * __builtin_amdgcn_rcpf(
                                __builtin_amdgcn_exp2f(zg) + 1.f);
          float vo = __builtin_amdgcn_rcpf(1.f + __builtin_amdgcn_exp2f(-zo));
          c = vf * c + vi * vg;
          hout = vo * (1.f - 2.f * __builtin_amdgcn_rcpf(
                               __builtin_amdgcn_exp2f(2.f * LOG2E * c) + 1.f));
          ushort_t hv = f2bf(hout);
          h0_lds[(p + 1) & 1][bat][cell] = hv;
          __builtin_nontemporal_store(hv, yg0 + (size_t)p * 128);
          p0v = p1v;
          int sn = (p + 2 < 300) ? p + 2 : 299;
          p1v = *(const f32x4*)(pg + (size_t)sn * 512);
          asm volatile("s_waitcnt vmcnt(6)" ::: "memory");
        } else if (p == 300) {
          asm volatile("s_waitcnt vmcnt(0)" ::: "memory");
        }
        LSTM_BAR();
        if (tid == 0) {
          if (p >= 3 && p < 300)
            __hip_atomic_store(flag0, (unsigned int)(p - 3), __ATOMIC_RELAXED,
                               __HIP_MEMORY_SCOPE_AGENT);
          else if (p == 300)
            __hip_atomic_store(flag0, 300u, __ATOMIC_RELAXED,
                               __HIP_MEMORY_SCOPE_AGENT);
        }
      }
      outH[(b0 + bat) * 128 + cell] = hout;
      outC[(b0 + bat) * 128 + cell] = c;
    } else {
      // ---------------- layer 1 waves ----------------
      bf16x8 aW[4][4];
#pragma unroll
      for (int j = 0; j < 4; ++j) {
        int rho = (4 * w + j) * 16 + col;
        int src = gperm(rho);
#pragma unroll
        for (int kt = 0; kt < 4; ++kt) {
          const float* s1 = whh1 + src * 128 + kt * 32 + kg * 8;
          bf16x8 f1;
#pragma unroll
          for (int qq = 0; qq < 8; ++qq) f1[qq] = (short)f2bf(s1[qq] * wsc);
          aW[j][kt] = f1;
        }
      }
      float bi = b1[cell] * LOG2E, bff = b1[128 + cell] * LOG2E;
      float bgg = b1[256 + cell] * (2.f * LOG2E), boo = b1[384 + cell] * LOG2E;
      const float* pg = pre1 + (size_t)(b0 + bat) * 300 * 512 + 4 * cell;
      ushort_t* yg = y1 + (size_t)(b0 + bat) * 300 * 128 + cell;
      float c = 0.f, hout = 0.f;
      unsigned int fc = 0;
      f32x4 p0v = {0.f, 0.f, 0.f, 0.f}, p1v = p0v;
      __syncthreads();

      for (int p = 0; p < 300 + LSTM_LAG; ++p) {
        if (p == LSTM_LAG - 2) {
          while (fc < 1) {
            fc = __hip_atomic_load(flag1, __ATOMIC_RELAXED,
                                   __HIP_MEMORY_SCOPE_AGENT);
            if (fc < 1) __builtin_amdgcn_s_sleep(2);
          }
          asm volatile("" ::: "memory");
          p0v = __builtin_nontemporal_load((const f32x4*)(pg));
        } else if (p == LSTM_LAG - 1) {
          while (fc < 2) {
            fc = __hip_atomic_load(flag1, __ATOMIC_RELAXED,
                                   __HIP_MEMORY_SCOPE_AGENT);
            if (fc < 2) __builtin_amdgcn_s_sleep(2);
          }
          asm volatile("" ::: "memory");
          p1v = __builtin_nontemporal_load((const f32x4*)(pg + 512));
        } else if (p >= LSTM_LAG) {
          int t = p - LSTM_LAG;
          const ushort_t* hb = h1_lds[t & 1][bat];
          bf16x8 bfr[4];
#pragma unroll
          for (int kt = 0; kt < 4; ++kt)
            bfr[kt] = *(const bf16x8*)(hb + kt * 32 + kg * 8);
          f32x4 a0 = {0.f, 0.f, 0.f, 0.f}, a1 = a0, a2 = a0, a3 = a0;
#pragma unroll
          for (int kt = 0; kt < 4; ++kt) {
            a0 = __builtin_amdgcn_mfma_f32_16x16x32_bf16(aW[0][kt], bfr[kt], a0, 0, 0, 0);
            a1 = __builtin_amdgcn_mfma_f32_16x16x32_bf16(aW[1][kt], bfr[kt], a1, 0, 0, 0);
            a2 = __builtin_amdgcn_mfma_f32_16x16x32_bf16(aW[2][kt], bfr[kt], a2, 0, 0, 0);
            a3 = __builtin_amdgcn_mfma_f32_16x16x32_bf16(aW[3][kt], bfr[kt], a3, 0, 0, 0);
          }
          f32x4 z = a0;
          if (q == 1) z = a1;
          if (q == 2) z = a2;
          if (q == 3) z = a3;
          float zi = z[0] + p0v[0] + bi;
          float zf = z[1] + p0v[1] + bff;
          float zg = z[2] + p0v[2] + bgg;
          float zo = z[3] + p0v[3] + boo;
          float vi = __builtin_amdgcn_rcpf(1.f + __builtin_amdgcn_exp2f(-zi));
          float vf = __builtin_amdgcn_rcpf(1.f + __builtin_amdgcn_exp2f(-zf));
          float vg = 1.f - 2.f * __builtin_amdgcn_rcpf(
                                __builtin_amdgcn_exp2f(zg) + 1.f);
          float vo = __builtin_amdgcn_rcpf(1.f + __builtin_amdgcn_exp2f(-zo));
          c = vf * c + vi * vg;
          hout = vo * (1.f - 2.f * __builtin_amdgcn_rcpf(
                               __builtin_amdgcn_exp2f(2.f * LOG2E * c) + 1.f));
          ushort_t hv = f2bf(hout);
          h1_lds[(t + 1) & 1][bat][cell] = hv;
          __builtin_nontemporal_store(hv, yg + (size_t)t * 128);
          p0v = p1v;
          if (t + 2 < 300) {
            unsigned int need = (unsigned int)(t + 3);
            if (fc < need) {
              do {
                fc = __hip_atomic_load(flag1, __ATOMIC_RELAXED,
                                       __HIP_MEMORY_SCOPE_AGENT);
                if (fc < need) __builtin_amdgcn_s_sleep(2);
              } while (fc < need);
              asm volatile("" ::: "memory");
            }
            p1v = __builtin_nontemporal_load(
                (const f32x4*)(pg + (size_t)(t + 2) * 512));
          }
        }
        LSTM_BAR();
      }
      outH[4096 + (b0 + bat) * 128 + cell] = hout;
      outC[4096 + (b0 + bat) * 128 + cell] = c;
    }
  } else {
    // ---------------- u-blocks: pre1[t] = Wih1 @ y0[t], 12-step chunks ------
    int g = blockIdx.x - 8;
    int b0 = g * 4;
    unsigned int* flag0 = &flags[g * 32];
    unsigned int* flag1 = &flags[g * 32 + 16];
    if (tid >= 512) {
      for (int k = 0; k < 25; ++k) __syncthreads();
      return;
    }
    bf16x8 aU[4][4];
#pragma unroll
    for (int j = 0; j < 4; ++j) {
      int rho = (4 * w + j) * 16 + col;
      int src = gperm(rho);
#pragma unroll
      for (int kt = 0; kt < 4; ++kt) {
        const float* s2 = wih1 + src * 128 + kt * 32 + kg * 8;
        bf16x8 f2;
#pragma unroll
        for (int qq = 0; qq < 8; ++qq) f2[qq] = (short)f2bf(s2[qq] * wsc);
        aU[j][kt] = f2;
      }
    }
    int bb = col & 3;   // batch within group (B-col -> (batch, step))
    int ts = col >> 2;  // step within 4-step col-tile
    const ushort_t* yb = y0 + ((size_t)(b0 + bb) * 300) * 128 + kg * 8;
    unsigned int fc = 0;
    for (int t0 = 0; t0 < 300; t0 += 12) {
      unsigned int need = (unsigned int)(t0 + 11);
      while (fc < need) {
        fc = __hip_atomic_load(flag0, __ATOMIC_RELAXED,
                               __HIP_MEMORY_SCOPE_AGENT);
        if (fc < need) __builtin_amdgcn_s_sleep(2);
      }
      asm volatile("" ::: "memory");
      f32x4 acc[4][3];
#pragma unroll
      for (int j = 0; j < 4; ++j)
#pragma unroll
        for (int ct = 0; ct < 3; ++ct) acc[j][ct] = (f32x4){0.f, 0.f, 0.f, 0.f};
#pragma unroll
      for (int ct = 0; ct < 3; ++ct) {
        int t = t0 + ct * 4 + ts;
        bf16x8 bfr[4];
#pragma unroll
        for (int kt = 0; kt < 4; ++kt)
          bfr[kt] = __builtin_nontemporal_load(
              (const bf16x8*)(yb + (size_t)t * 128 + kt * 32));
#pragma unroll
        for (int kt = 0; kt < 4; ++kt) {
          acc[0][ct] = __builtin_amdgcn_mfma_f32_16x16x32_bf16(aU[0][kt], bfr[kt], acc[0][ct], 0, 0, 0);
          acc[1][ct] = __builtin_amdgcn_mfma_f32_16x16x32_bf16(aU[1][kt], bfr[kt], acc[1][ct], 0, 0, 0);
          acc[2][ct] = __builtin_amdgcn_mfma_f32_16x16x32_bf16(aU[2][kt], bfr[kt], acc[2][ct], 0, 0, 0);
          acc[3][ct] = __builtin_amdgcn_mfma_f32_16x16x32_bf16(aU[3][kt], bfr[kt], acc[3][ct], 0, 0, 0);
        }
      }
#pragma unroll
      for (int ct = 0; ct < 3; ++ct) {
        int t = t0 + ct * 4 + ts;
        float* pd = pre1 + ((size_t)(b0 + bb) * 300 + t) * 512 + kg * 4;
#pragma unroll
        for (int j = 0; j < 4; ++j)
          __builtin_nontemporal_store(acc[j][ct],
                                      (f32x4*)(pd + (4 * w + j) * 16));
      }
      asm volatile("s_waitcnt vmcnt(0)" ::: "memory");
      __syncthreads();
      if (tid == 0)
        __hip_atomic_store(flag1, (unsigned int)(t0 + 12), __ATOMIC_RELAXED,
                           __HIP_MEMORY_SCOPE_AGENT);
    }
  }
}

// ---------------- launch ----------------
extern "C" void kernel_launch(void* const* d_in, const int* in_sizes, int n_in,
                              void* d_out, int out_size, void* d_ws,
                              size_t ws_size, hipStream_t stream) {
  const float* mv = (const float*)d_in[0];
  const float* boxes = (const float*)d_in[1];
  const int* track_ids = (const int*)d_in[2];
  const float* conv1_w = (const float*)d_in[3];
  const float* conv1_b = (const float*)d_in[4];
  const float* bn1_g = (const float*)d_in[5];
  const float* bn1_b = (const float*)d_in[6];
  const float* conv2_w = (const float*)d_in[7];
  const float* conv2_b = (const float*)d_in[8];
  const float* bn2_g = (const float*)d_in[9];
  const float* bn2_b = (const float*)d_in[10];
  const float* conv3_w = (const float*)d_in[11];
  const float* conv3_b = (const float*)d_in[12];
  const float* bn3_g = (const float*)d_in[13];
  const float* bn3_b = (const float*)d_in[14];
  const float* agg_w1 = (const float*)d_in[15];
  const float* agg_b1 = (const float*)d_in[16];
  const float* agg_w2 = (const float*)d_in[17];
  const float* agg_b2 = (const float*)d_in[18];
  const float* bx_w1 = (const float*)d_in[19];
  const float* bx_b1 = (const float*)d_in[20];
  const float* bx_w2 = (const float*)d_in[21];
  const float* bx_b2 = (const float*)d_in[22];
  const float* id_table = (const float*)d_in[23];
  const float* proj_w = (const float*)d_in[24];
  const float* proj_b = (const float*)d_in[25];
  const float* l0_wih = (const float*)d_in[27];
  const float* l0_whh = (const float*)d_in[28];
  const float* l0_b = (const float*)d_in[29];
  const float* l1_wih = (const float*)d_in[30];
  const float* l1_whh = (const float*)d_in[31];
  const float* l1_b = (const float*)d_in[32];
  const float* hb_w1 = (const float*)d_in[33];
  const float* hb_b1 = (const float*)d_in[34];
  const float* hb_w2 = (const float*)d_in[35];
  const float* hb_b2 = (const float*)d_in[36];
  const float* hc_w1 = (const float*)d_in[37];
  const float* hc_b1 = (const float*)d_in[38];
  const float* hc_w2 = (const float*)d_in[39];
  const float* hc_b2 = (const float*)d_in[40];
  const float* ht_w1 = (const float*)d_in[41];
  const float* ht_b1 = (const float*)d_in[42];
  const float* ht_w2 = (const float*)d_in[43];
  const float* ht_b2 = (const float*)d_in[44];

  char* wsb = (char*)d_ws;
  float* pre0 = (float*)(wsb + 0);               // 19,660,800 B
  ushort_t* hid = (ushort_t*)(wsb + 0);          // 14,745,600 B (alias, tail)
  ushort_t* y0g = (ushort_t*)(wsb + 19660800);   // 2,457,600 B
  float* gf = (float*)(wsb + 22118400);          // 8,192 B
  ushort_t* obj = (ushort_t*)(wsb + 22126592);   // 3,686,400 B
  float* pre1 = (float*)(wsb + 25812992);        // 19,660,800 B
  ushort_t* y1b = (ushort_t*)(wsb + 45473792);   // 2,457,600 B
  unsigned int* flags = (unsigned int*)(wsb + 47931392);  // 1,024 B
  ushort_t* wAp = (ushort_t*)(wsb + 47932416);   // 196,608 B
  ushort_t* whid = (ushort_t*)(wsb + 48129024);  // 196,608 B
  ushort_t* wt2 = (ushort_t*)(wsb + 48325632);   // 512,000 B
  float* bhid = (float*)(wsb + 48837632);        // 3,072 B
  float* l0bp = (float*)(wsb + 48840704);        // 2,048 B
  ushort_t* wc2 = (ushort_t*)(wsb + 48908288);   // 36,864 B
  ushort_t* wc3 = (ushort_t*)(wsb + 48945152);   // 73,728 B

  float* outB = (float*)d_out;    // [32,300,4]
  float* outC = outB + 38400;     // [32,300,2]
  float* outT = outB + 57600;     // [32,300,1000]
  float* outH = outB + 9657600;   // [2,32,128]
  float* outCc = outB + 9665792;  // [2,32,128]

  hipMemsetAsync(gf, 0, 2048 * sizeof(float), stream);
  hipMemsetAsync(flags, 0, 1024, stream);

  front_kernel<<<6789, 256, 0, stream>>>(
      mv, boxes, track_ids, agg_w1, agg_b1, agg_w2, agg_b2, bx_w1, bx_b1,
      bx_w2, bx_b2, id_table, obj, conv2_w, conv3_w, l0_wih, proj_w, proj_b,
      l0_b, hb_w1, hc_w1, ht_w1, ht_w2, hb_b1, hc_b1, ht_b1, wc2, wc3, wAp,
      l0bp, whid, wt2, bhid);
  convstack_kernel<<<dim3(25, 32), 256, 0, stream>>>(
      mv, conv1_w, conv1_b, bn1_g, bn1_b, wc2, conv2_b, bn2_g, bn2_b, wc3,
      conv3_b, bn3_g, bn3_b, gf);
  gemm_bf16w_kernel<0, false, true><<<dim3(75, 8), 256, 0, stream>>>(
      obj, 192, wAp, l0bp, pre0, 512, 9600, 512, 192, l0_wih, gf);
  lstm_fused_kernel<<<16, 1024, 0, stream>>>(pre0, l0_whh, l1_wih, l1_whh,
                                             l1_b, pre1, y0g, y1b, outH,
                                             outCc, flags);
  gemm_bf16w_kernel<1, true, false><<<dim3(75, 12), 256, 0, stream>>>(
      y1b, 128, whid, bhid, hid, 768, 9600, 768, 128, nullptr, nullptr);
  head_small_kernel<<<225, 256, 0, stream>>>(hid, hb_w2, hb_b2, hc_w2, hc_b2,
                                             outB, outC);
  gemm_bf16w_kernel<0, false, false><<<dim3(75, 16), 256, 0, stream>>>(
      hid + 512, 768, wt2, ht_b2, outT, 1000, 9600, 1000, 256, nullptr,
      nullptr);
}

// Round 11
// 472.618 us; speedup vs baseline: 1.1043x; 1.1043x over previous
//
#include <hip/hip_runtime.h>
#include <hip/hip_bf16.h>
#include <math.h>

typedef unsigned short ushort_t;
typedef __attribute__((ext_vector_type(8))) short bf16x8;
typedef __attribute__((ext_vector_type(4))) float f32x4;

#define LOG2E 1.4426950408889634f

// ---------------- helpers ----------------
__device__ __forceinline__ float sigf(float x) {
  x = fminf(fmaxf(x, -30.f), 30.f);
  return 1.f / (1.f + __expf(-x));
}
__device__ __forceinline__ ushort_t f2bf(float x) {
  unsigned int b = __float_as_uint(x);
  unsigned int lsb = (b >> 16) & 1u;
  b += 0x7fffu + lsb;
  return (ushort_t)(b >> 16);
}
__device__ __forceinline__ float bf2f(ushort_t u) {
  return __uint_as_float(((unsigned int)u) << 16);
}
// gate scale for exp2-form activations: rows of gate g (pos&3==2) carry
// 2*log2e, others log2e. Applied at every pre-activation producer.
__device__ __forceinline__ float gsc(int g3) {
  return (g3 == 2) ? (2.f * LOG2E) : LOG2E;
}

#define NPIX 3600
// gate-row permutation: LSTM row-space position rho holds real gate row
// G(rho) = (rho&3)*128 + (rho>>2)  => per cell c, gates i,f,g,o sit at
// positions 4c..4c+3.
__device__ __forceinline__ int gperm(int rho) {
  return ((rho & 3) << 7) + (rho >> 2);
}

// ---- front: wprep (blocks 0-1988) + box stats (1989-6788) ------------------
__global__ __launch_bounds__(256) void front_kernel(
    const float* __restrict__ mv, const float* __restrict__ boxes,
    const int* __restrict__ ids, const float* __restrict__ agg_w1,
    const float* __restrict__ agg_b1, const float* __restrict__ agg_w2,
    const float* __restrict__ agg_b2, const float* __restrict__ bx_w1,
    const float* __restrict__ bx_b1, const float* __restrict__ bx_w2,
    const float* __restrict__ bx_b2, const float* __restrict__ id_table,
    ushort_t* __restrict__ obj_out, const float* __restrict__ conv2_w,
    const float* __restrict__ conv3_w, const float* __restrict__ wih0,
    const float* __restrict__ projW, const float* __restrict__ projb,
    const float* __restrict__ l0_b, const float* __restrict__ hbw1,
    const float* __restrict__ hcw1, const float* __restrict__ htw1,
    const float* __restrict__ htw2, const float* __restrict__ hbb1,
    const float* __restrict__ hcb1, const float* __restrict__ htb1,
    ushort_t* __restrict__ wc2, ushort_t* __restrict__ wc3,
    ushort_t* __restrict__ wAp, float* __restrict__ l0bp,
    ushort_t* __restrict__ whid, ushort_t* __restrict__ wt2,
    float* __restrict__ bhid) {
  if (blockIdx.x < 1989) {
    // ---- weight prep ----
    int i = blockIdx.x * 256 + threadIdx.x;
    if (i < 18432) {  // conv2 w -> [oc][kt][ic] bf16
      int oc = i / 288, r = i % 288, kt = r / 32, ic = r % 32;
      wc2[i] = f2bf(conv2_w[((oc * 32 + ic) * 3 + kt / 3) * 3 + kt % 3]);
      return;
    }
    i -= 18432;
    if (i < 36864) {  // conv3 w -> [oc][c][kt][ic] bf16
      int oc = i / 576, r = i % 576, c = r / 288, r2 = r % 288;
      int kt = r2 / 32, icl = r2 % 32, ic = c * 32 + icl;
      wc3[i] = f2bf(conv3_w[((oc * 64 + ic) * 3 + kt / 3) * 3 + kt % 3]);
      return;
    }
    i -= 36864;
    if (i < 98304) {  // W' = wih0[:, :128] @ projW, permuted + gate-scaled
      int n = i / 192, k = i % 192;
      int src = gperm(n);
      float a = 0.f;
      if (k < 160) {
        const float* wr = wih0 + src * 192;
        for (int j = 0; j < 128; ++j) a = fmaf(wr[j], projW[j * 160 + k], a);
      }
      wAp[i] = f2bf(a * gsc(n & 3));
      return;
    }
    i -= 98304;
    if (i < 512) {  // l0b' = l0_b + wih0[:, :128] @ proj_b, permuted + scaled
      int src = gperm(i);
      float a = l0_b[src];
      const float* wr = wih0 + src * 192;
      for (int j = 0; j < 128; ++j) a = fmaf(wr[j], projb[j], a);
      l0bp[i] = a * gsc(i & 3);
      return;
    }
    i -= 512;
    if (i < 98304) {  // concat head hidden weights
      int row = i >> 7, c = i & 127;
      float v = (row < 256)   ? hbw1[row * 128 + c]
                : (row < 512) ? hcw1[(row - 256) * 128 + c]
                              : htw1[(row - 512) * 128 + c];
      whid[i] = f2bf(v);
      return;
    }
    i -= 98304;
    if (i < 256000) {
      wt2[i] = f2bf(htw2[i]);
      return;
    }
    i -= 256000;
    if (i < 768)
      bhid[i] = (i < 256) ? hbb1[i] : (i < 512) ? hcb1[i - 256] : htb1[i - 512];
    return;
  }
  // ---- box stats + small MLPs: 2 boxes per block ----
  int bx = blockIdx.x - 1989;
  __shared__ float obj[2][160];
  __shared__ float hm[2][32];
  __shared__ float hbx[2][32];
  __shared__ float stats[2][8];
  __shared__ float boxf[2][4];
  __shared__ float red[2][2][8];
  int h = threadIdx.x >> 7;
  int t = threadIdx.x & 127;
  int blk = bx * 2 + h;  // box index 0..9599
  int b = blk / 300;
  float bx0 = boxes[blk * 4 + 0], by0 = boxes[blk * 4 + 1];
  float bx1 = boxes[blk * 4 + 2], by1 = boxes[blk * 4 + 3];
  const float HI = (float)(60.0 - 1e-6);
  float gx1 = fminf(fmaxf(bx0 * 60.f, 0.f), HI);
  float gy1 = fminf(fmaxf(by0 * 60.f, 0.f), HI);
  float gx2 = fminf(fmaxf(bx1 * 60.f, 0.f), HI);
  float gy2 = fminf(fmaxf(by1 * 60.f, 0.f), HI);
  float fx1 = floorf(gx1), fy1 = floorf(gy1);
  float fx2 = fmaxf(fx1 + 1.f, ceilf(gx2));
  float fy2 = fmaxf(fy1 + 1.f, ceilf(gy2));
  int ix1 = (int)fx1, iy1 = (int)fy1, ix2 = (int)fx2, iy2 = (int)fy2;
  int w = ix2 - ix1, hgt = iy2 - iy1;
  int area = w * hgt;
  float s0 = 0.f, s1 = 0.f, q0 = 0.f, q1 = 0.f;
  float mn0 = 1e9f, mn1 = 1e9f, mx0 = -1e9f, mx1 = -1e9f;
  const float* mv0 = mv + b * 2 * NPIX;
  const float* mv1 = mv0 + NPIX;
  for (int i = t; i < area; i += 128) {
    int r = i / w, cc = i - r * w;
    int yy = iy1 + r, xx = ix1 + cc;
    float v0 = mv0[yy * 60 + xx];
    float v1 = mv1[yy * 60 + xx];
    s0 += v0; q0 += v0 * v0; mn0 = fminf(mn0, v0); mx0 = fmaxf(mx0, v0);
    s1 += v1; q1 += v1 * v1; mn1 = fminf(mn1, v1); mx1 = fmaxf(mx1, v1);
  }
#pragma unroll
  for (int off = 32; off; off >>= 1) {
    s0 += __shfl_down(s0, off); s1 += __shfl_down(s1, off);
    q0 += __shfl_down(q0, off); q1 += __shfl_down(q1, off);
    mn0 = fminf(mn0, __shfl_down(mn0, off));
    mn1 = fminf(mn1, __shfl_down(mn1, off));
    mx0 = fmaxf(mx0, __shfl_down(mx0, off));
    mx1 = fmaxf(mx1, __shfl_down(mx1, off));
  }
  if ((t & 63) == 0) {
    int wv = t >> 6;
    red[h][wv][0] = s0; red[h][wv][1] = s1;
    red[h][wv][2] = q0; red[h][wv][3] = q1;
    red[h][wv][4] = mn0; red[h][wv][5] = mn1;
    red[h][wv][6] = mx0; red[h][wv][7] = mx1;
  }
  __syncthreads();
  if (t == 0) {
    float S0 = red[h][0][0] + red[h][1][0], S1 = red[h][0][1] + red[h][1][1];
    float Q0 = red[h][0][2] + red[h][1][2], Q1 = red[h][0][3] + red[h][1][3];
    float MN0 = fminf(red[h][0][4], red[h][1][4]);
    float MN1 = fminf(red[h][0][5], red[h][1][5]);
    float MX0 = fmaxf(red[h][0][6], red[h][1][6]);
    float MX1 = fmaxf(red[h][0][7], red[h][1][7]);
    float cnt = (float)area;
    float mean0 = S0 / cnt, mean1 = S1 / cnt;
    float var0 = (Q0 - cnt * mean0 * mean0) / fmaxf(cnt - 1.f, 1.f);
    float var1 = (Q1 - cnt * mean1 * mean1) / fmaxf(cnt - 1.f, 1.f);
    float sd0 = (cnt > 1.f) ? sqrtf(fmaxf(var0, 1e-12f)) : 0.f;
    float sd1 = (cnt > 1.f) ? sqrtf(fmaxf(var1, 1e-12f)) : 0.f;
    stats[h][0] = mean0; stats[h][1] = mean1; stats[h][2] = sd0;
    stats[h][3] = sd1; stats[h][4] = MN0; stats[h][5] = MX0;
    stats[h][6] = MN1; stats[h][7] = MX1;
    boxf[h][0] = bx0; boxf[h][1] = by0; boxf[h][2] = bx1; boxf[h][3] = by1;
  }
  __syncthreads();
  if (t < 32) {
    float a = agg_b1[t];
#pragma unroll
    for (int k = 0; k < 8; ++k) a = fmaf(stats[h][k], agg_w1[t * 8 + k], a);
    hm[h][t] = fmaxf(a, 0.f);
  } else if (t < 64) {
    int j = t - 32;
    float a = bx_b1[j];
#pragma unroll
    for (int k = 0; k < 4; ++k) a = fmaf(boxf[h][k], bx_w1[j * 4 + k], a);
    hbx[h][j] = fmaxf(a, 0.f);
  }
  __syncthreads();
  if (t < 64) {
    float a = bx_b2[t];
#pragma unroll
    for (int k = 0; k < 32; ++k) a = fmaf(hbx[h][k], bx_w2[t * 32 + k], a);
    obj[h][t] = a;
  } else {
    int j = t - 64;
    float a = agg_b2[j];
#pragma unroll
    for (int k = 0; k < 32; ++k) a = fmaf(hm[h][k], agg_w2[j * 32 + k], a);
    obj[h][96 + j] = a;
  }
  if (t < 32) {
    int id = ids[blk];
    id = min(max(id, 0), 999);
    obj[h][64 + t] = id_table[id * 32 + t];
  }
  __syncthreads();
  obj_out[(size_t)blk * 192 + t] = f2bf(obj[h][t]);
  if (t < 32) {
    obj_out[(size_t)blk * 192 + 128 + t] = f2bf(obj[h][128 + t]);
    obj_out[(size_t)blk * 192 + 160 + t] = 0;
  }
}

// ---------- fused conv1+conv2+conv3+avgpool: one block = 14x14 out tile -----
__global__ __launch_bounds__(256) void convstack_kernel(
    const float* __restrict__ mv, const float* __restrict__ c1w,
    const float* __restrict__ c1b, const float* __restrict__ bg1,
    const float* __restrict__ bb1, const ushort_t* __restrict__ wc2,
    const float* __restrict__ c2b, const float* __restrict__ bg2,
    const float* __restrict__ bb2, const ushort_t* __restrict__ wc3,
    const float* __restrict__ c3b, const float* __restrict__ bg3,
    const float* __restrict__ bb3, float* __restrict__ gf) {
  __shared__ char smem[25920 + 37152];           // 63,072 B
  ushort_t* c1_lds = (ushort_t*)smem;            // [324][40] bf16
  ushort_t* c2_lds = (ushort_t*)(smem + 25920);  // [258][72] bf16 (+2 pad pos)
  float* mv_lds = (float*)(smem + 25920);        // [2][20][20] (aliases c2)
  int tid = threadIdx.x;
  int wv = tid >> 6, lane = tid & 63;
  int col = lane & 15, kg = lane >> 4;
  int b = blockIdx.y, tile = blockIdx.x;
  int tq = tile / 5, tr = tile % 5;
  int ty0 = (tq == 4) ? 46 : tq * 14;
  int tx0 = (tr == 4) ? 46 : tr * 14;
  // stage mv rows [ty0-3, ty0+16] x cols [tx0-3, tx0+16], zero-padded
  for (int i = tid; i < 800; i += 256) {
    int r = i % 400;
    int ch = i / 400, yy = r / 20, xx = r % 20;
    int gy = ty0 - 3 + yy, gx = tx0 - 3 + xx;
    float v = 0.f;
    if (gy >= 0 && gy < 60 && gx >= 0 && gx < 60)
      v = mv[((size_t)(b * 2 + ch) * 60 + gy) * 60 + gx];
    mv_lds[i] = v;
  }
  __syncthreads();
  // conv1 (2->32, BN+ReLU): 18x18 out, rows [ty0-2, ty0+15]
  {
    int oc = tid & 31;
    float s = bg1[oc] * rsqrtf(1.f + 1e-5f);
    float bias = fmaf(c1b[oc], s, bb1[oc]);
    float w1r[18];
#pragma unroll
    for (int k = 0; k < 18; ++k) w1r[k] = c1w[oc * 18 + k];
    for (int pos = tid >> 5; pos < 324; pos += 8) {
      int yy = pos / 18, xx = pos % 18;
      int gy = ty0 - 2 + yy, gx = tx0 - 2 + xx;
      ushort_t out = 0;
      if (gy >= 0 && gy < 60 && gx >= 0 && gx < 60) {
        float acc = 0.f;
#pragma unroll
        for (int ic = 0; ic < 2; ++ic)
#pragma unroll
          for (int ky = 0; ky < 3; ++ky)
#pragma unroll
            for (int kx = 0; kx < 3; ++kx)
              acc = fmaf(mv_lds[ic * 400 + (yy + ky) * 20 + xx + kx],
                         w1r[ic * 9 + ky * 3 + kx], acc);
        out = f2bf(fmaxf(fmaf(acc, s, bias), 0.f));
      }
      c1_lds[pos * 40 + oc] = out;
    }
  }
  __syncthreads();  // conv1 done; mv reads done (c2_lds aliasing now safe)
  int oc2 = wv * 16 + col;
  // conv2 (32->64, MFMA, BN+ReLU): 16x16 out, rows [ty0-1, ty0+14]
  {
    bf16x8 bw2[9];
#pragma unroll
    for (int kt = 0; kt < 9; ++kt)
      bw2[kt] = *(const bf16x8*)(wc2 + oc2 * 288 + kt * 32 + kg * 8);
    f32x4 a2[16];
#pragma unroll
    for (int m = 0; m < 16; ++m) a2[m] = (f32x4){0.f, 0.f, 0.f, 0.f};
#pragma unroll
    for (int kt = 0; kt < 9; ++kt) {
      int ky = kt / 3, kx = kt % 3;
#pragma unroll
      for (int m = 0; m < 16; ++m) {
        bf16x8 af = *(const bf16x8*)(
            &c1_lds[((m + ky) * 18 + col + kx) * 40 + kg * 8]);
        a2[m] =
            __builtin_amdgcn_mfma_f32_16x16x32_bf16(af, bw2[kt], a2[m], 0, 0, 0);
      }
    }
    float s = bg2[oc2] * rsqrtf(1.f + 1e-5f);
    float bias = fmaf(c2b[oc2], s, bb2[oc2]);
#pragma unroll
    for (int m = 0; m < 16; ++m) {
      int gy = ty0 - 1 + m;
#pragma unroll
      for (int r = 0; r < 4; ++r) {
        int gx = tx0 - 1 + kg * 4 + r;
        ushort_t o = 0;
        if (gy >= 0 && gy < 60 && gx >= 0 && gx < 60)
          o = f2bf(fmaxf(fmaf(a2[m][r], s, bias), 0.f));
        c2_lds[(m * 16 + kg * 4 + r) * 72 + oc2] = o;
      }
    }
  }
  __syncthreads();
  // conv3 (64->64, MFMA, BN+ReLU) + masked avgpool accumulate
  {
    bf16x8 bw3[2][9];
#pragma unroll
    for (int c = 0; c < 2; ++c)
#pragma unroll
      for (int kt = 0; kt < 9; ++kt)
        bw3[c][kt] =
            *(const bf16x8*)(wc3 + oc2 * 576 + c * 288 + kt * 32 + kg * 8);
    f32x4 a3[14];
#pragma unroll
    for (int m = 0; m < 14; ++m) a3[m] = (f32x4){0.f, 0.f, 0.f, 0.f};
#pragma unroll
    for (int c = 0; c < 2; ++c)
#pragma unroll
      for (int kt = 0; kt < 9; ++kt) {
        int ky = kt / 3, kx = kt % 3;
#pragma unroll
        for (int m = 0; m < 14; ++m) {
          bf16x8 af = *(const bf16x8*)(
              &c2_lds[((m + ky) * 16 + col + kx) * 72 + c * 32 + kg * 8]);
          a3[m] = __builtin_amdgcn_mfma_f32_16x16x32_bf16(af, bw3[c][kt],
                                                          a3[m], 0, 0, 0);
        }
      }
    float s = bg3[oc2] * rsqrtf(1.f + 1e-5f);
    float bias = fmaf(c3b[oc2], s, bb3[oc2]);
    float pool = 0.f;
#pragma unroll
    for (int m = 0; m < 14; ++m) {
      bool ym = (tq != 4) || (m >= 10);
#pragma unroll
      for (int r = 0; r < 4; ++r) {
        int px = kg * 4 + r;
        bool xm = (px < 14) && ((tr != 4) || (px >= 10));
        if (ym && xm) pool += fmaxf(fmaf(a3[m][r], s, bias), 0.f);
      }
    }
    pool += __shfl_xor(pool, 16);
    pool += __shfl_xor(pool, 32);
    if (lane < 16) atomicAdd(&gf[b * 64 + oc2], pool);
  }
}

// ---------------- bf16-W MFMA GEMM: C = act(A@W^T + b [+ gvec]) -------------
// GVEC=true: the gvec contribution (wih0[:,128:] @ gf / 3600, permuted,
// gate-scaled) is computed INLINE per block (<=2 batches x 64 cols, 64-FMA
// dots) instead of a separate gvec kernel + buffer.
template <int ACT, bool OBF16, bool GVEC>
__global__ __launch_bounds__(256) void gemm_bf16w_kernel(
    const ushort_t* __restrict__ A, int lda, const ushort_t* __restrict__ W,
    const float* __restrict__ bias, void* __restrict__ C, int ldc, int M,
    int N, int K, const float* __restrict__ wih0,
    const float* __restrict__ gf) {
  __shared__ ushort_t As[128 * 64];
  __shared__ ushort_t Ws[64 * 64];
  __shared__ float gvl[2][64];
  int tid = threadIdx.x;
  int wv = tid >> 6, lane = tid & 63;
  int col = lane & 15, kg = lane >> 4;
  int wm = wv >> 1, wn = wv & 1;
  int m0 = blockIdx.x * 128, n0 = blockIdx.y * 64;
  int bA = m0 / 300;
  if (GVEC && tid < 128) {
    int sel = tid >> 6;  // 0/1: batch bA / bA+1
    int nn = tid & 63;
    int n = n0 + nn;
    int bb = min(bA + sel, 31);
    const float* wr = wih0 + gperm(n) * 192 + 128;
    const float* gg = gf + bb * 64;
    float a = 0.f;
#pragma unroll
    for (int k = 0; k < 64; ++k) a = fmaf(wr[k], gg[k], a);
    gvl[sel][nn] = a * (1.f / 3600.f) * gsc(n & 3);
  }
  f32x4 acc[4][2];
#pragma unroll
  for (int i = 0; i < 4; ++i)
#pragma unroll
    for (int j = 0; j < 2; ++j) acc[i][j] = (f32x4){0.f, 0.f, 0.f, 0.f};

  int nk = K >> 6;
  for (int kc = 0; kc < nk; ++kc) {
    if (kc) __syncthreads();
#pragma unroll
    for (int q = 0; q < 4; ++q) {
      int idx = q * 256 + tid;
      int row = idx >> 3, ch = idx & 7;
      uint4 v =
          *(const uint4*)(A + (size_t)(m0 + row) * lda + kc * 64 + ch * 8);
      *(uint4*)(&As[row * 64 + ((ch * 8) ^ ((row & 7) << 3))]) = v;
    }
#pragma unroll
    for (int q = 0; q < 2; ++q) {
      int idx = q * 256 + tid;
      int row = idx >> 3, ch = idx & 7;
      int n = n0 + row;
      uint4 v = make_uint4(0, 0, 0, 0);
      if (n < N) v = *(const uint4*)(W + (size_t)n * K + kc * 64 + ch * 8);
      *(uint4*)(&Ws[row * 64 + ((ch * 8) ^ ((row & 7) << 3))]) = v;
    }
    __syncthreads();
#pragma unroll
    for (int ks = 0; ks < 2; ++ks) {
      bf16x8 bfr[2], afr[4];
#pragma unroll
      for (int ni = 0; ni < 2; ++ni) {
        int row = wn * 32 + ni * 16 + col;
        bfr[ni] = *(const bf16x8*)(
            &Ws[row * 64 + ((ks * 32 + kg * 8) ^ ((row & 7) << 3))]);
      }
#pragma unroll
      for (int mi = 0; mi < 4; ++mi) {
        int row = wm * 64 + mi * 16 + col;
        afr[mi] = *(const bf16x8*)(
            &As[row * 64 + ((ks * 32 + kg * 8) ^ ((row & 7) << 3))]);
      }
#pragma unroll
      for (int mi = 0; mi < 4; ++mi)
#pragma unroll
        for (int ni = 0; ni < 2; ++ni)
          acc[mi][ni] = __builtin_amdgcn_mfma_f32_16x16x32_bf16(
              afr[mi], bfr[ni], acc[mi][ni], 0, 0, 0);
    }
  }
#pragma unroll
  for (int ni = 0; ni < 2; ++ni) {
    int n = n0 + wn * 32 + ni * 16 + col;
    float bn = (n < N) ? bias[n] : 0.f;
#pragma unroll
    for (int mi = 0; mi < 4; ++mi) {
      int mbase = m0 + wm * 64 + mi * 16 + kg * 4;
#pragma unroll
      for (int r = 0; r < 4; ++r) {
        float v = acc[mi][ni][r] + bn;
        if (GVEC) v += gvl[(mbase + r) / 300 - bA][wn * 32 + ni * 16 + col];
        if (ACT == 1) v = fmaxf(v, 0.f);
        if (n < N) {
          if (OBF16)
            ((ushort_t*)C)[(size_t)(mbase + r) * ldc + n] = f2bf(v);
          else
            ((float*)C)[(size_t)(mbase + r) * ldc + n] = v;
        }
      }
    }
  }
}

// ---------------- small heads: hb2 (sigmoid, N=4) + hc2 (N=2) ---------------
__global__ __launch_bounds__(256) void head_small_kernel(
    const ushort_t* __restrict__ hid, const float* __restrict__ wb2,
    const float* __restrict__ bb2, const float* __restrict__ wc2,
    const float* __restrict__ bc2, float* __restrict__ outB,
    float* __restrict__ outC) {
  int idx = blockIdx.x * 256 + threadIdx.x;  // 9600*6
  int row = idx / 6, j = idx % 6;
  const ushort_t* h = hid + (size_t)row * 768 + (j < 4 ? 0 : 256);
  const float* wrow = (j < 4) ? wb2 + j * 256 : wc2 + (j - 4) * 256;
  float acc = (j < 4) ? bb2[j] : bc2[j - 4];
  for (int k = 0; k < 256; k += 8) {
    uint4 hv = *(const uint4*)(h + k);
    unsigned int ww[4] = {hv.x, hv.y, hv.z, hv.w};
#pragma unroll
    for (int q = 0; q < 4; ++q) {
      acc = fmaf(bf2f((ushort_t)(ww[q] & 0xffff)), wrow[k + 2 * q], acc);
      acc = fmaf(bf2f((ushort_t)(ww[q] >> 16)), wrow[k + 2 * q + 1], acc);
    }
  }
  float v = (j < 4) ? sigf(acc) : acc;
  if (j < 4) outB[row * 4 + j] = v;
  else outC[row * 2 + (j - 4)] = v;
}

// ---------------- fused pipelined 2-layer LSTM scan (= v9 core) --------------
// Proven-best scan: 24 blocks (L0 0-7 / L1 8-15 / u 16-23), 8 waves/block,
// 1 cell/lane, ONE barrier/step. v14's merged L0+L1 block REVERTED: the
// shared barrier coupled both layers' critical paths (2x ds_read burst into
// the same CU's LDS per period + 16-wave convoy + flag-poll coupling),
// costing +50us. Wave-level overlap needs independent barriers.
#define LSTM_BAR() asm volatile("s_waitcnt lgkmcnt(0)\n\ts_barrier" ::: "memory")

__global__ __launch_bounds__(512) void lstm_fused_kernel(
    const float* __restrict__ pre0,  // [32][300][512] f32, permuted+scaled
    const float* __restrict__ whh0,  // [512,128]
    const float* __restrict__ wih1,  // [512,128]
    const float* __restrict__ whh1,  // [512,128]
    const float* __restrict__ b1,    // [512]
    float* __restrict__ pre1,        // [32][300][512] f32, permuted+scaled
    ushort_t* __restrict__ y0,       // [32][300][128] bf16 (L0 -> u)
    ushort_t* __restrict__ y1,       // [32][300][128] bf16
    float* __restrict__ outH, float* __restrict__ outC,
    unsigned int* __restrict__ flags)  // [8*32] padded
{
  __shared__ ushort_t h_lds[2][4][160];
  int tid = threadIdx.x;
  int w = tid >> 6, lane = tid & 63;
  int col = lane & 15, kg = lane >> 4;
  int bat = col & 3, q = col >> 2;
  int cell = (4 * w + q) * 4 + kg;
  float wsc = gsc(col & 3);  // A-row = col -> gate = col&3

  if (blockIdx.x < 8) {
    // ---------------- layer 0 ----------------
    int g = blockIdx.x;
    int b0 = g * 4;
    unsigned int* flagp = &flags[g * 32];
    for (int i = tid; i < 2 * 4 * 160; i += 512) ((ushort_t*)h_lds)[i] = 0;
    bf16x8 aW0[4][4];
#pragma unroll
    for (int j = 0; j < 4; ++j) {
      int rho = (4 * w + j) * 16 + col;
      int src = gperm(rho);
#pragma unroll
      for (int kt = 0; kt < 4; ++kt) {
        const float* s1 = whh0 + src * 128 + kt * 32 + kg * 8;
        bf16x8 f1;
#pragma unroll
        for (int qq = 0; qq < 8; ++qq) f1[qq] = (short)f2bf(s1[qq] * wsc);
        aW0[j][kt] = f1;
      }
    }
    const float* pg = pre0 + (size_t)(b0 + bat) * 300 * 512 + 4 * cell;
    ushort_t* yg0 = y0 + ((size_t)(b0 + bat) * 300) * 128 + cell;
    float c = 0.f, hout = 0.f;
    f32x4 p0v = *(const f32x4*)(pg);
    f32x4 p1v = *(const f32x4*)(pg + 512);
    __syncthreads();

    for (int s = 0; s < 300; ++s) {
      const ushort_t* hb = h_lds[s & 1][bat];
      bf16x8 bfr[4];
#pragma unroll
      for (int kt = 0; kt < 4; ++kt)
        bfr[kt] = *(const bf16x8*)(hb + kt * 32 + kg * 8);
      f32x4 a0 = {0.f, 0.f, 0.f, 0.f}, a1 = a0, a2 = a0, a3 = a0;
#pragma unroll
      for (int kt = 0; kt < 4; ++kt) {
        a0 = __builtin_amdgcn_mfma_f32_16x16x32_bf16(aW0[0][kt], bfr[kt], a0, 0, 0, 0);
        a1 = __builtin_amdgcn_mfma_f32_16x16x32_bf16(aW0[1][kt], bfr[kt], a1, 0, 0, 0);
        a2 = __builtin_amdgcn_mfma_f32_16x16x32_bf16(aW0[2][kt], bfr[kt], a2, 0, 0, 0);
        a3 = __builtin_amdgcn_mfma_f32_16x16x32_bf16(aW0[3][kt], bfr[kt], a3, 0, 0, 0);
      }
      // static select of own tile (q uniform per lane; cndmask, no scratch)
      f32x4 z = a0;
      if (q == 1) z = a1;
      if (q == 2) z = a2;
      if (q == 3) z = a3;
      {
        float zi = z[0] + p0v[0];
        float zf = z[1] + p0v[1];
        float zg = z[2] + p0v[2];
        float zo = z[3] + p0v[3];
        float vi = __builtin_amdgcn_rcpf(1.f + __builtin_amdgcn_exp2f(-zi));
        float vf = __builtin_amdgcn_rcpf(1.f + __builtin_amdgcn_exp2f(-zf));
        float vg = 1.f - 2.f * __builtin_amdgcn_rcpf(
                              __builtin_amdgcn_exp2f(zg) + 1.f);
        float vo = __builtin_amdgcn_rcpf(1.f + __builtin_amdgcn_exp2f(-zo));
        c = vf * c + vi * vg;
        hout = vo * (1.f - 2.f * __builtin_amdgcn_rcpf(
                             __builtin_amdgcn_exp2f(2.f * LOG2E * c) + 1.f));
        ushort_t hv = f2bf(hout);
        h_lds[(s + 1) & 1][bat][cell] = hv;
        __builtin_nontemporal_store(hv, yg0 + (size_t)s * 128);
        p0v = p1v;
        int sn = (s + 2 < 300) ? s + 2 : 299;
        p1v = *(const f32x4*)(pg + (size_t)sn * 512);
      }
      // 2 vmem ops/step; vmcnt(6) = 3 steps in flight => y0(<=s-3) retired
      asm volatile("s_waitcnt vmcnt(6)" ::: "memory");
      LSTM_BAR();
      if (tid == 0 && s >= 3)
        __hip_atomic_store(flagp, (unsigned int)(s - 3), __ATOMIC_RELAXED,
                           __HIP_MEMORY_SCOPE_AGENT);
    }
    asm volatile("s_waitcnt vmcnt(0)" ::: "memory");
    __syncthreads();
    if (tid == 0)
      __hip_atomic_store(flagp, 300u, __ATOMIC_RELAXED,
                         __HIP_MEMORY_SCOPE_AGENT);
    outH[(b0 + bat) * 128 + cell] = hout;
    outC[(b0 + bat) * 128 + cell] = c;
  } else if (blockIdx.x < 16) {
    // ---------------- layer 1 (mirror of L0, p from pre1 via u-flag) --------
    int g = blockIdx.x - 8;
    int b0 = g * 4;
    unsigned int* flagp = &flags[g * 32 + 16];
    for (int i = tid; i < 2 * 4 * 160; i += 512) ((ushort_t*)h_lds)[i] = 0;
    bf16x8 aW[4][4];
#pragma unroll
    for (int j = 0; j < 4; ++j) {
      int rho = (4 * w + j) * 16 + col;
      int src = gperm(rho);
#pragma unroll
      for (int kt = 0; kt < 4; ++kt) {
        const float* s1 = whh1 + src * 128 + kt * 32 + kg * 8;
        bf16x8 f1;
#pragma unroll
        for (int qq = 0; qq < 8; ++qq) f1[qq] = (short)f2bf(s1[qq] * wsc);
        aW[j][kt] = f1;
      }
    }
    float bi = b1[cell] * LOG2E, bff = b1[128 + cell] * LOG2E;
    float bgg = b1[256 + cell] * (2.f * LOG2E), boo = b1[384 + cell] * LOG2E;
    const float* pg = pre1 + (size_t)(b0 + bat) * 300 * 512 + 4 * cell;
    ushort_t* yg = y1 + (size_t)(b0 + bat) * 300 * 128 + cell;
    float c = 0.f, hout = 0.f;
    unsigned int fc = 0;
    f32x4 p0v, p1v;
    do {
      fc = __hip_atomic_load(flagp, __ATOMIC_RELAXED,
                             __HIP_MEMORY_SCOPE_AGENT);
      if (fc < 1) __builtin_amdgcn_s_sleep(2);
    } while (fc < 1);
    asm volatile("" ::: "memory");
    p0v = __builtin_nontemporal_load((const f32x4*)(pg));
    while (fc < 2) {
      fc = __hip_atomic_load(flagp, __ATOMIC_RELAXED,
                             __HIP_MEMORY_SCOPE_AGENT);
      if (fc < 2) __builtin_amdgcn_s_sleep(2);
    }
    asm volatile("" ::: "memory");
    p1v = __builtin_nontemporal_load((const f32x4*)(pg + 512));
    __syncthreads();

    for (int t = 0; t < 300; ++t) {
      // eager flag read: issue now, consume at the prefetch point below
      unsigned int fcn = __hip_atomic_load(flagp, __ATOMIC_RELAXED,
                                           __HIP_MEMORY_SCOPE_AGENT);
      const ushort_t* hb = h_lds[t & 1][bat];
      bf16x8 bfr[4];
#pragma unroll
      for (int kt = 0; kt < 4; ++kt)
        bfr[kt] = *(const bf16x8*)(hb + kt * 32 + kg * 8);
      f32x4 a0 = {0.f, 0.f, 0.f, 0.f}, a1 = a0, a2 = a0, a3 = a0;
#pragma unroll
      for (int kt = 0; kt < 4; ++kt) {
        a0 = __builtin_amdgcn_mfma_f32_16x16x32_bf16(aW[0][kt], bfr[kt], a0, 0, 0, 0);
        a1 = __builtin_amdgcn_mfma_f32_16x16x32_bf16(aW[1][kt], bfr[kt], a1, 0, 0, 0);
        a2 = __builtin_amdgcn_mfma_f32_16x16x32_bf16(aW[2][kt], bfr[kt], a2, 0, 0, 0);
        a3 = __builtin_amdgcn_mfma_f32_16x16x32_bf16(aW[3][kt], bfr[kt], a3, 0, 0, 0);
      }
      f32x4 z = a0;
      if (q == 1) z = a1;
      if (q == 2) z = a2;
      if (q == 3) z = a3;
      {
        float zi = z[0] + p0v[0] + bi;
        float zf = z[1] + p0v[1] + bff;
        float zg = z[2] + p0v[2] + bgg;
        float zo = z[3] + p0v[3] + boo;
        float vi = __builtin_amdgcn_rcpf(1.f + __builtin_amdgcn_exp2f(-zi));
        float vf = __builtin_amdgcn_rcpf(1.f + __builtin_amdgcn_exp2f(-zf));
        float vg = 1.f - 2.f * __builtin_amdgcn_rcpf(
                              __builtin_amdgcn_exp2f(zg) + 1.f);
        float vo = __builtin_amdgcn_rcpf(1.f + __builtin_amdgcn_exp2f(-zo));
        c = vf * c + vi * vg;
        hout = vo * (1.f - 2.f * __builtin_amdgcn_rcpf(
                             __builtin_amdgcn_exp2f(2.f * LOG2E * c) + 1.f));
        ushort_t hv = f2bf(hout);
        h_lds[(t + 1) & 1][bat][cell] = hv;
        __builtin_nontemporal_store(hv, yg + (size_t)t * 128);
        p0v = p1v;
        if (t + 2 < 300) {
          unsigned int need = (unsigned int)(t + 3);
          if (fcn > fc) fc = fcn;
          if (fc < need) {
            do {
              fc = __hip_atomic_load(flagp, __ATOMIC_RELAXED,
                                     __HIP_MEMORY_SCOPE_AGENT);
              if (fc < need) __builtin_amdgcn_s_sleep(2);
            } while (fc < need);
            asm volatile("" ::: "memory");
          }
          p1v = __builtin_nontemporal_load(
              (const f32x4*)(pg + (size_t)(t + 2) * 512));
        }
      }
      LSTM_BAR();
    }
    outH[4096 + (b0 + bat) * 128 + cell] = hout;
    outC[4096 + (b0 + bat) * 128 + cell] = c;
  } else {
    // ---------------- u-blocks: pre1[t] = Wih1 @ y0[t], 12-step chunks ------
    int g = blockIdx.x - 16;
    int b0 = g * 4;
    unsigned int* flag0 = &flags[g * 32];
    unsigned int* flag1 = &flags[g * 32 + 16];
    bf16x8 aU[4][4];
#pragma unroll
    for (int j = 0; j < 4; ++j) {
      int rho = (4 * w + j) * 16 + col;
      int src = gperm(rho);
#pragma unroll
      for (int kt = 0; kt < 4; ++kt) {
        const float* s2 = wih1 + src * 128 + kt * 32 + kg * 8;
        bf16x8 f2;
#pragma unroll
        for (int qq = 0; qq < 8; ++qq) f2[qq] = (short)f2bf(s2[qq] * wsc);
        aU[j][kt] = f2;
      }
    }
    int bb = col & 3;   // batch within group (B-col -> (batch, step))
    int ts = col >> 2;  // step within 4-step col-tile
    const ushort_t* yb = y0 + ((size_t)(b0 + bb) * 300) * 128 + kg * 8;
    unsigned int fc = 0;
    for (int t0 = 0; t0 < 300; t0 += 12) {
      unsigned int need = (unsigned int)(t0 + 11);
      while (fc < need) {
        fc = __hip_atomic_load(flag0, __ATOMIC_RELAXED,
                               __HIP_MEMORY_SCOPE_AGENT);
        if (fc < need) __builtin_amdgcn_s_sleep(2);
      }
      asm volatile("" ::: "memory");
      f32x4 acc[4][3];
#pragma unroll
      for (int j = 0; j < 4; ++j)
#pragma unroll
        for (int ct = 0; ct < 3; ++ct) acc[j][ct] = (f32x4){0.f, 0.f, 0.f, 0.f};
#pragma unroll
      for (int ct = 0; ct < 3; ++ct) {
        int t = t0 + ct * 4 + ts;
        bf16x8 bfr[4];
#pragma unroll
        for (int kt = 0; kt < 4; ++kt)
          bfr[kt] = __builtin_nontemporal_load(
              (const bf16x8*)(yb + (size_t)t * 128 + kt * 32));
#pragma unroll
        for (int kt = 0; kt < 4; ++kt) {
          acc[0][ct] = __builtin_amdgcn_mfma_f32_16x16x32_bf16(aU[0][kt], bfr[kt], acc[0][ct], 0, 0, 0);
          acc[1][ct] = __builtin_amdgcn_mfma_f32_16x16x32_bf16(aU[1][kt], bfr[kt], acc[1][ct], 0, 0, 0);
          acc[2][ct] = __builtin_amdgcn_mfma_f32_16x16x32_bf16(aU[2][kt], bfr[kt], acc[2][ct], 0, 0, 0);
          acc[3][ct] = __builtin_amdgcn_mfma_f32_16x16x32_bf16(aU[3][kt], bfr[kt], acc[3][ct], 0, 0, 0);
        }
      }
#pragma unroll
      for (int ct = 0; ct < 3; ++ct) {
        int t = t0 + ct * 4 + ts;
        float* pd = pre1 + ((size_t)(b0 + bb) * 300 + t) * 512 + kg * 4;
#pragma unroll
        for (int j = 0; j < 4; ++j)
          __builtin_nontemporal_store(acc[j][ct],
                                      (f32x4*)(pd + (4 * w + j) * 16));
      }
      asm volatile("s_waitcnt vmcnt(0)" ::: "memory");
      __syncthreads();
      if (tid == 0)
        __hip_atomic_store(flag1, (unsigned int)(t0 + 12), __ATOMIC_RELAXED,
                           __HIP_MEMORY_SCOPE_AGENT);
    }
  }
}

// ---------------- launch ----------------
extern "C" void kernel_launch(void* const* d_in, const int* in_sizes, int n_in,
                              void* d_out, int out_size, void* d_ws,
                              size_t ws_size, hipStream_t stream) {
  const float* mv = (const float*)d_in[0];
  const float* boxes = (const float*)d_in[1];
  const int* track_ids = (const int*)d_in[2];
  const float* conv1_w = (const float*)d_in[3];
  const float* conv1_b = (const float*)d_in[4];
  const float* bn1_g = (const float*)d_in[5];
  const float* bn1_b = (const float*)d_in[6];
  const float* conv2_w = (const float*)d_in[7];
  const float* conv2_b = (const float*)d_in[8];
  const float* bn2_g = (const float*)d_in[9];
  const float* bn2_b = (const float*)d_in[10];
  const float* conv3_w = (const float*)d_in[11];
  const float* conv3_b = (const float*)d_in[12];
  const float* bn3_g = (const float*)d_in[13];
  const float* bn3_b = (const float*)d_in[14];
  const float* agg_w1 = (const float*)d_in[15];
  const float* agg_b1 = (const float*)d_in[16];
  const float* agg_w2 = (const float*)d_in[17];
  const float* agg_b2 = (const float*)d_in[18];
  const float* bx_w1 = (const float*)d_in[19];
  const float* bx_b1 = (const float*)d_in[20];
  const float* bx_w2 = (const float*)d_in[21];
  const float* bx_b2 = (const float*)d_in[22];
  const float* id_table = (const float*)d_in[23];
  const float* proj_w = (const float*)d_in[24];
  const float* proj_b = (const float*)d_in[25];
  const float* l0_wih = (const float*)d_in[27];
  const float* l0_whh = (const float*)d_in[28];
  const float* l0_b = (const float*)d_in[29];
  const float* l1_wih = (const float*)d_in[30];
  const float* l1_whh = (const float*)d_in[31];
  const float* l1_b = (const float*)d_in[32];
  const float* hb_w1 = (const float*)d_in[33];
  const float* hb_b1 = (const float*)d_in[34];
  const float* hb_w2 = (const float*)d_in[35];
  const float* hb_b2 = (const float*)d_in[36];
  const float* hc_w1 = (const float*)d_in[37];
  const float* hc_b1 = (const float*)d_in[38];
  const float* hc_w2 = (const float*)d_in[39];
  const float* hc_b2 = (const float*)d_in[40];
  const float* ht_w1 = (const float*)d_in[41];
  const float* ht_b1 = (const float*)d_in[42];
  const float* ht_w2 = (const float*)d_in[43];
  const float* ht_b2 = (const float*)d_in[44];

  char* wsb = (char*)d_ws;
  float* pre0 = (float*)(wsb + 0);               // 19,660,800 B
  ushort_t* hid = (ushort_t*)(wsb + 0);          // 14,745,600 B (alias, tail)
  ushort_t* y0g = (ushort_t*)(wsb + 19660800);   // 2,457,600 B
  float* gf = (float*)(wsb + 22118400);          // 8,192 B
  ushort_t* obj = (ushort_t*)(wsb + 22126592);   // 3,686,400 B
  float* pre1 = (float*)(wsb + 25812992);        // 19,660,800 B
  ushort_t* y1b = (ushort_t*)(wsb + 45473792);   // 2,457,600 B
  unsigned int* flags = (unsigned int*)(wsb + 47931392);  // 1,024 B
  ushort_t* wAp = (ushort_t*)(wsb + 47932416);   // 196,608 B
  ushort_t* whid = (ushort_t*)(wsb + 48129024);  // 196,608 B
  ushort_t* wt2 = (ushort_t*)(wsb + 48325632);   // 512,000 B
  float* bhid = (float*)(wsb + 48837632);        // 3,072 B
  float* l0bp = (float*)(wsb + 48840704);        // 2,048 B
  ushort_t* wc2 = (ushort_t*)(wsb + 48908288);   // 36,864 B
  ushort_t* wc3 = (ushort_t*)(wsb + 48945152);   // 73,728 B

  float* outB = (float*)d_out;    // [32,300,4]
  float* outC = outB + 38400;     // [32,300,2]
  float* outT = outB + 57600;     // [32,300,1000]
  float* outH = outB + 9657600;   // [2,32,128]
  float* outCc = outB + 9665792;  // [2,32,128]

  hipMemsetAsync(gf, 0, 2048 * sizeof(float), stream);
  hipMemsetAsync(flags, 0, 1024, stream);

  front_kernel<<<6789, 256, 0, stream>>>(
      mv, boxes, track_ids, agg_w1, agg_b1, agg_w2, agg_b2, bx_w1, bx_b1,
      bx_w2, bx_b2, id_table, obj, conv2_w, conv3_w, l0_wih, proj_w, proj_b,
      l0_b, hb_w1, hc_w1, ht_w1, ht_w2, hb_b1, hc_b1, ht_b1, wc2, wc3, wAp,
      l0bp, whid, wt2, bhid);
  convstack_kernel<<<dim3(25, 32), 256, 0, stream>>>(
      mv, conv1_w, conv1_b, bn1_g, bn1_b, wc2, conv2_b, bn2_g, bn2_b, wc3,
      conv3_b, bn3_g, bn3_b, gf);
  gemm_bf16w_kernel<0, false, true><<<dim3(75, 8), 256, 0, stream>>>(
      obj, 192, wAp, l0bp, pre0, 512, 9600, 512, 192, l0_wih, gf);
  lstm_fused_kernel<<<24, 512, 0, stream>>>(pre0, l0_whh, l1_wih, l1_whh,
                                            l1_b, pre1, y0g, y1b, outH, outCc,
                                            flags);
  gemm_bf16w_kernel<1, true, false><<<dim3(75, 12), 256, 0, stream>>>(
      y1b, 128, whid, bhid, hid, 768, 9600, 768, 128, nullptr, nullptr);
  head_small_kernel<<<225, 256, 0, stream>>>(hid, hb_w2, hb_b2, hc_w2, hc_b2,
                                             outB, outC);
  gemm_bf16w_kernel<0, false, false><<<dim3(75, 16), 256, 0, stream>>>(
      hid + 512, 768, wt2, ht_b2, outT, 1000, 9600, 1000, 256, nullptr,
      nullptr);
}